// Round 9
// baseline (111.295 us; speedup 1.0000x reference)
//
#include <hip/hip_runtime.h>

// FeatureEmbedder: out[b, f*64+d] = relu(x[b,f] * W[f,d] + b[f,d])
// x: [16384, 128] f32, W: [128, 64] f32, b: [128, 64] f32
// out: [16384, 8192] f32  (512 MB -> HBM-write-bound)
//
// R9: isolate the x-path. Experiment matrix so far:
//           scattered-stores   block-linear-stores
// direct x      117.3 (R0)         THIS KERNEL
// LDS x         128.6 (R4)         102.0 (R5/R6/R8)
// LDS staging costs +11 us on the scattered layout (per-iter ds_read ->
// lgkmcnt wait ~120cy x 256 iters ~= 12.8 us serial stall). R5 bundled the
// layout win WITH the LDS path; this round keeps R5's proven block-linear
// store sweep (block b owns contiguous 1 MB, rows 32b..32b+31) but reads x
// directly from global: 16-lane broadcast, 16 KB/block working set (L1-
// resident), independent loads the compiler pipelines deep in the vmcnt
// FIFO. No LDS, no syncthreads.

#define BATCH 16384
#define NFEAT 128
#define EMBD  64
#define ROW4  (NFEAT * EMBD / 4)   // 2048 float4 per output row

typedef float vfloat4 __attribute__((ext_vector_type(4)));

__global__ __launch_bounds__(256) void feature_embed_kernel(
    const float* __restrict__ x,
    const vfloat4* __restrict__ W4,
    const vfloat4* __restrict__ B4,
    vfloat4* __restrict__ out4) {

    const int tid = threadIdx.x;          // 0..255
    const int b   = blockIdx.x;           // 0..511

    // Per-thread column set: col4 = j*256 + tid, j = 0..7. Hoist W/b.
    vfloat4 w[8], bb[8];
    #pragma unroll
    for (int j = 0; j < 8; ++j) {
        w[j]  = W4[j * 256 + tid];
        bb[j] = B4[j * 256 + tid];
    }

    const int fs = tid >> 4;              // within-j feature sub-index, 0..15
    const float* xb = x + b * 32 * NFEAT + fs;   // + r*NFEAT + j*16
    vfloat4* outb = out4 + b * 32 * ROW4; // this block's 1 MB region

    #pragma unroll 4
    for (int r = 0; r < 32; ++r) {
        const float* xr = xb + r * NFEAT;
        vfloat4* outr = outb + r * ROW4 + tid;
        #pragma unroll
        for (int j = 0; j < 8; ++j) {
            const float xv = xr[j * 16];  // global broadcast, L1-resident
            vfloat4 o;
            o.x = fmaxf(fmaf(xv, w[j].x, bb[j].x), 0.0f);
            o.y = fmaxf(fmaf(xv, w[j].y, bb[j].y), 0.0f);
            o.z = fmaxf(fmaf(xv, w[j].z, bb[j].z), 0.0f);
            o.w = fmaxf(fmaf(xv, w[j].w, bb[j].w), 0.0f);
            // Linear sweep: iteration (r*8+j) writes the next 4 KB chunk.
            outr[j * 256] = o;
        }
    }
}

extern "C" void kernel_launch(void* const* d_in, const int* in_sizes, int n_in,
                              void* d_out, int out_size, void* d_ws, size_t ws_size,
                              hipStream_t stream) {
    const float*   x  = (const float*)d_in[0];
    const vfloat4* W4 = (const vfloat4*)d_in[1];
    const vfloat4* B4 = (const vfloat4*)d_in[2];
    vfloat4* out4     = (vfloat4*)d_out;

    // 512 blocks x 256 threads; block b writes rows [32b, 32b+32) linearly.
    feature_embed_kernel<<<512, 256, 0, stream>>>(x, W4, B4, out4);
}

// Round 10
// 99.607 us; speedup vs baseline: 1.1173x; 1.1173x over previous
//
#include <hip/hip_runtime.h>

// FeatureEmbedder: out[b, f*64+d] = relu(x[b,f] * W[f,d] + b[f,d])
// x: [16384, 128] f32, W: [128, 64] f32, b: [128, 64] f32
// out: [16384, 8192] f32  (512 MB -> HBM-write-bound)
//
// R10: drop to ~64 concurrent write streams. Plateau evidence: R5/R6/R8 all
// 102.0-102.2 us (5.1 TB/s) regardless of ordering/stream-count 512->256;
// R7/R9 worse. Page-locality model predicts a cliff only when streams per
// DRAM channel fall below the bank count (~16-32); 512 and 256 are both far
// above it. This kernel: 64 blocks x 1024 threads, block b sweeps a private
// CONTIGUOUS 8 MB region (rows 256b..256b+255) -> 64 device-wide streams,
// 2 orders below R0. Per-CU store rate needed at target: ~98 GB/s, within
// issue capability. Structure = R5 scaled: 8 slabs of 32 rows; x slab
// double-buffered in LDS (prefetch = 1 float4/thread/slab vs 64 stores ->
// negligible vmcnt coupling); 2 hoisted W/b pairs; conflict-free broadcast
// ds_reads; pure-store main stream.

#define BATCH 16384
#define NFEAT 128
#define EMBD  64
#define ROW4  (NFEAT * EMBD / 4)   // 2048 float4 per output row

typedef float vfloat4 __attribute__((ext_vector_type(4)));

__global__ __launch_bounds__(1024) void feature_embed_kernel(
    const vfloat4* __restrict__ x4,
    const vfloat4* __restrict__ W4,
    const vfloat4* __restrict__ B4,
    vfloat4* __restrict__ out4) {

    __shared__ float xs[2][32 * NFEAT];   // 2 x 16 KB slab buffers

    const int tid = threadIdx.x;          // 0..1023
    const int b   = blockIdx.x;           // 0..63

    // Thread's columns: col4 = j*1024 + tid, j = 0..1. Hoist W/b.
    vfloat4 wv[2], bv[2];
    wv[0] = W4[tid];        wv[1] = W4[1024 + tid];
    bv[0] = B4[tid];        bv[1] = B4[1024 + tid];

    // Block owns x rows [256b, 256b+256): 8 slabs x 32 rows.
    // One slab = 32 rows x 32 float4 = 1024 float4 -> 1 float4/thread.
    const vfloat4* xb = x4 + b * (256 * NFEAT / 4);

    ((vfloat4*)xs[0])[tid] = xb[tid];     // stage slab 0
    __syncthreads();

    const int fs = tid >> 4;              // feature sub-index, 0..63
    vfloat4* outb = out4 + b * 256 * ROW4;  // this block's 8 MB region

    for (int s = 0; s < 8; ++s) {
        // Prefetch next slab into the other buffer (overlaps with stores).
        if (s < 7)
            ((vfloat4*)xs[(s + 1) & 1])[tid] = xb[(s + 1) * 1024 + tid];

        const float* xsl = xs[s & 1];
        vfloat4* outs = outb + s * 32 * ROW4;

        #pragma unroll 4
        for (int r = 0; r < 32; ++r) {
            const float* xr = xsl + r * NFEAT;
            vfloat4* outr = outs + r * ROW4 + tid;
            #pragma unroll
            for (int j = 0; j < 2; ++j) {
                const float xv = xr[j * 64 + fs];   // ds_read broadcast
                vfloat4 o;
                o.x = fmaxf(fmaf(xv, wv[j].x, bv[j].x), 0.0f);
                o.y = fmaxf(fmaf(xv, wv[j].y, bv[j].y), 0.0f);
                o.z = fmaxf(fmaf(xv, wv[j].z, bv[j].z), 0.0f);
                o.w = fmaxf(fmaf(xv, wv[j].w, bv[j].w), 0.0f);
                // Linear sweep of the block's 8 MB region, 16 KB per (r).
                outr[j * 1024] = o;
            }
        }
        __syncthreads();  // prefetch visible; buffer free for next overwrite
    }
}

extern "C" void kernel_launch(void* const* d_in, const int* in_sizes, int n_in,
                              void* d_out, int out_size, void* d_ws, size_t ws_size,
                              hipStream_t stream) {
    const vfloat4* x4 = (const vfloat4*)d_in[0];
    const vfloat4* W4 = (const vfloat4*)d_in[1];
    const vfloat4* B4 = (const vfloat4*)d_in[2];
    vfloat4* out4     = (vfloat4*)d_out;

    // 64 blocks x 1024 threads; block b writes rows [256b, 256b+256) linearly.
    feature_embed_kernel<<<64, 1024, 0, stream>>>(x4, W4, B4, out4);
}